// Round 5
// baseline (312.392 us; speedup 1.0000x reference)
//
#include <hip/hip_runtime.h>

typedef __bf16 bfx8 __attribute__((ext_vector_type(8)));
typedef float f32x4 __attribute__((ext_vector_type(4)));
typedef unsigned short u16x8 __attribute__((ext_vector_type(8)));

#define MFMA16(a, b, c) __builtin_amdgcn_mfma_f32_16x16x32_bf16((a), (b), (c), 0, 0, 0)

#define GLOAD16(gp, lp)                                                        \
  __builtin_amdgcn_global_load_lds(                                            \
      (const __attribute__((address_space(1))) unsigned int*)(gp),             \
      (__attribute__((address_space(3))) unsigned int*)(lp), 16, 0, 0)

// Geometry: x (8, 256, 16384) fp32; mem (200, 256) fp32; out (8, 256, 16384) fp32.
// Slots padded 200 -> 256 with zero rows.

// ---------------- prep: mem -> bf16 hi/lo + permuted-transposed hi ----------------
// MTp[c][kidx] = hi(mem[sigma(kidx)][c]), sigma(32ks+8h+4t+r) -> slot 32ks+16t+4h+r,
// so the PV B-operand is a pure in-register repack of the score accumulators.
__global__ __launch_bounds__(256) void prep_mem(const float* __restrict__ mem,
                                                unsigned short* __restrict__ Mh,
                                                unsigned short* __restrict__ Ml,
                                                unsigned short* __restrict__ MTp) {
  const int s = blockIdx.x;   // slot (padded)
  const int c = threadIdx.x;  // channel
  const float v = (s < 200) ? mem[s * 256 + c] : 0.0f;
  const __bf16 hi = (__bf16)v;
  const __bf16 lo = (__bf16)(v - (float)hi);
  const unsigned short hib = __builtin_bit_cast(unsigned short, hi);
  const unsigned short lob = __builtin_bit_cast(unsigned short, lo);
  Mh[s * 256 + c] = hib;
  Ml[s * 256 + c] = lob;
  const int ks = s >> 5, w = s & 31;
  const int t = w >> 4, hh = (w >> 2) & 3, rr = w & 3;
  MTp[c * 256 + (ks * 32 + hh * 8 + t * 4 + rr)] = hib;
}

// ---------------- fused kernel ----------------
// Block = 4 waves x 16 tokens = 64 tokens. Grid = 2048. 32KB LDS, <=128 VGPR
// -> 4 blocks/CU (16 waves/CU): sync-drain stalls overlap across blocks.
// Proven R2 structure: full-drain __syncthreads, ping-pong buffers, swizzle.
__global__ __launch_bounds__(256, 4) void fused_mem_attn(
    const float* __restrict__ x, const unsigned short* __restrict__ Mh,
    const unsigned short* __restrict__ Ml, const unsigned short* __restrict__ MTp,
    float* __restrict__ out) {
  __shared__ alignas(128) char lds[32768];

  const int tid = threadIdx.x;
  const int wave = tid >> 6;
  const int lane = tid & 63;
  const int t16 = lane & 15;
  const int h = lane >> 4;

  // Staging: thread owns physical 16B-block P = it*256+tid of a 16KB slice;
  // fetches logical L = P ^ ((P>>3)&7) (involution) -> LDS swizzled, dest linear.
  int srcOff[4];
#pragma unroll
  for (int it = 0; it < 4; ++it) {
    const int P = it * 256 + tid;
    const int L = P ^ ((P >> 3) & 7);
    srcOff[it] = (L >> 2) * 512 + (L & 3) * 16;  // byte offset in [256 rows][64B]
  }

  // Reader-side swizzled block byte offset within a 1KB (16-row) tile.
  const int q16 = ((((t16 << 2) + h) ^ (t16 >> 1)) << 4);

  const long gtok0 = (long)blockIdx.x * 64 + (long)(wave * 16);
  const int b = (int)(gtok0 >> 14);
  const int n0 = (int)(gtok0 & 16383);
  const float* xb = x + ((long)b << 22) + n0 + t16;

  const char* MhB = (const char*)Mh;
  const char* MlB = (const char*)Ml;
  const char* MTB = (const char*)MTp;

#define STAGE_MH(ks)                                                           \
  {                                                                            \
    char* dst_ = lds + (((ks) & 1) * 16384);                                   \
    _Pragma("unroll") for (int it = 0; it < 4; ++it) {                         \
      GLOAD16(MhB + srcOff[it] + (ks) * 64, dst_ + (it * 256 + tid) * 16);     \
    }                                                                          \
  }

#define STAGE_PV(k)                                                            \
  {                                                                            \
    char* dst_ = lds + (((k) & 1) * 16384);                                    \
    _Pragma("unroll") for (int it = 0; it < 4; ++it) {                         \
      GLOAD16(MTB + srcOff[it] + (k) * 64, dst_ + (it * 256 + tid) * 16);      \
    }                                                                          \
  }

#define XLOAD(ks)                                                              \
  _Pragma("unroll") for (int j = 0; j < 8; ++j) {                              \
    xr[(ks) & 1][j] = xb[(long)((ks) * 32 + h * 8 + j) << 14];                 \
  }

  float xr[2][8];
  f32x4 acc[14] = {};  // acc[13] stays exactly 0 (padding slots 208..223)

  STAGE_MH(0);
  XLOAD(0);

  // ---- score phase: S^T[slot][token], 3-pass hi/lo split ----
  // Sync at top publishes the buffer staged last iteration (full drain: safe).
#pragma unroll
  for (int ks = 0; ks < 8; ++ks) {
    __syncthreads();
    if (ks < 7) {
      STAGE_MH(ks + 1);
      XLOAD(ks + 1);
    } else {
      STAGE_PV(0);
    }

    bfx8 xh, xl;
#pragma unroll
    for (int j = 0; j < 8; ++j) {
      const float f = xr[ks & 1][j];
      const __bf16 hi = (__bf16)f;
      xh[j] = hi;
      xl[j] = (__bf16)(f - (float)hi);
    }

    const char* sb = lds + ((ks & 1) * 16384);
    __builtin_amdgcn_s_setprio(1);
#pragma unroll
    for (int tt = 0; tt < 13; ++tt) {  // slots >= 208 are dead (padding)
      const bfx8 ah = *(const bfx8*)(sb + tt * 1024 + q16);
      // lo-part A-fragment straight from L2 (register domain, no LDS ledger)
      const u16x8 mlu =
          *(const u16x8*)(MlB + (tt * 16 + t16) * 512 + ks * 64 + h * 16);
      const bfx8 al = __builtin_bit_cast(bfx8, mlu);
      acc[tt] = MFMA16(ah, xh, acc[tt]);
      acc[tt] = MFMA16(al, xh, acc[tt]);
      acc[tt] = MFMA16(ah, xl, acc[tt]);
    }
    __builtin_amdgcn_s_setprio(0);
  }

  // ---- softmax over slots (token column = lane&15; slot row = 4h+r) ----
  float m = -3.0e38f;
#pragma unroll
  for (int tt = 0; tt < 12; ++tt)
#pragma unroll
    for (int r = 0; r < 4; ++r) m = fmaxf(m, acc[tt][r]);
#pragma unroll
  for (int r = 0; r < 4; ++r)
    if (192 + h * 4 + r < 200) m = fmaxf(m, acc[12][r]);
  m = fmaxf(m, __shfl_xor(m, 16, 64));
  m = fmaxf(m, __shfl_xor(m, 32, 64));
  float s = 0.f;
#pragma unroll
  for (int tt = 0; tt < 12; ++tt)
#pragma unroll
    for (int r = 0; r < 4; ++r) {
      const float p = __expf(acc[tt][r] - m);
      acc[tt][r] = p;
      s += p;
    }
#pragma unroll
  for (int r = 0; r < 4; ++r) {
    const bool ok = (192 + h * 4 + r) < 200;
    const float p = ok ? __expf(acc[12][r] - m) : 0.f;
    acc[12][r] = p;
    s += p;
  }
  s += __shfl_xor(s, 16, 64);
  s += __shfl_xor(s, 32, 64);
  const float inv = 1.f / s;

  // ---- repack P into PV B-fragments in registers (sigma baked into MTp) ----
  bfx8 pb[7];
#pragma unroll
  for (int k = 0; k < 7; ++k)
#pragma unroll
    for (int j = 0; j < 4; ++j) {
      pb[k][j] = (__bf16)acc[2 * k][j];
      pb[k][j + 4] = (__bf16)acc[2 * k + 1][j];
    }

  // ---- PV: out^T[c][token] = sum_kidx MTp[c][kidx] * P[sigma(kidx)][token] ----
  f32x4 acc2[16] = {};
#pragma unroll
  for (int k = 0; k < 7; ++k) {
    __syncthreads();  // publishes PV(k) staged last iteration (full drain)
    if (k < 6) STAGE_PV(k + 1);
    const char* pv = lds + ((k & 1) * 16384);
    __builtin_amdgcn_s_setprio(1);
#pragma unroll
    for (int ct = 0; ct < 16; ++ct) {
      const bfx8 at = *(const bfx8*)(pv + ct * 1024 + q16);
      acc2[ct] = MFMA16(at, pb[k], acc2[ct]);
    }
    __builtin_amdgcn_s_setprio(0);
  }

  // ---- epilogue: normalize, store out[b][c][n] ----
  float* ob = out + ((long)b << 22) + n0 + t16;
#pragma unroll
  for (int ct = 0; ct < 16; ++ct)
#pragma unroll
    for (int r = 0; r < 4; ++r) {
      ob[(long)(ct * 16 + h * 4 + r) << 14] = acc2[ct][r] * inv;
    }
#undef STAGE_MH
#undef STAGE_PV
#undef XLOAD
}

extern "C" void kernel_launch(void* const* d_in, const int* in_sizes, int n_in,
                              void* d_out, int out_size, void* d_ws, size_t ws_size,
                              hipStream_t stream) {
  const float* x = (const float*)d_in[0];
  const float* mem = (const float*)d_in[1];
  float* out = (float*)d_out;

  unsigned short* Mh = (unsigned short*)d_ws;  // [256][256] bf16 hi
  unsigned short* Ml = Mh + 256 * 256;         // [256][256] bf16 lo
  unsigned short* MTp = Ml + 256 * 256;        // [256][256] bf16 hi, [c][kidx] permuted

  prep_mem<<<dim3(256), dim3(256), 0, stream>>>(mem, Mh, Ml, MTp);
  fused_mem_attn<<<dim3(2048), dim3(256), 0, stream>>>(x, Mh, Ml, MTp, out);
}

// Round 6
// 106.111 us; speedup vs baseline: 2.9440x; 2.9440x over previous
//
#include <hip/hip_runtime.h>

typedef __bf16 bfx8 __attribute__((ext_vector_type(8)));
typedef float f32x4 __attribute__((ext_vector_type(4)));
typedef unsigned short u16x8 __attribute__((ext_vector_type(8)));

#define MFMA16(a, b, c) __builtin_amdgcn_mfma_f32_16x16x32_bf16((a), (b), (c), 0, 0, 0)

#define GLOAD16(gp, lp)                                                        \
  __builtin_amdgcn_global_load_lds(                                            \
      (const __attribute__((address_space(1))) unsigned int*)(gp),             \
      (__attribute__((address_space(3))) unsigned int*)(lp), 16, 0, 0)

// Geometry: x (8, 256, 16384) fp32; mem (200, 256) fp32; out (8, 256, 16384) fp32.
// Slots padded 200 -> 256 with zero rows.

// ---------------- prep: mem -> bf16 hi/lo + permuted-transposed hi ----------------
// MTp[c][kidx] = hi(mem[sigma(kidx)][c]), sigma(32ks+8h+4t+r) -> slot 32ks+16t+4h+r,
// so the PV B-operand is a pure in-register repack of the score accumulators.
__global__ __launch_bounds__(256) void prep_mem(const float* __restrict__ mem,
                                                unsigned short* __restrict__ Mh,
                                                unsigned short* __restrict__ Ml,
                                                unsigned short* __restrict__ MTp) {
  const int s = blockIdx.x;   // slot (padded)
  const int c = threadIdx.x;  // channel
  const float v = (s < 200) ? mem[s * 256 + c] : 0.0f;
  const __bf16 hi = (__bf16)v;
  const __bf16 lo = (__bf16)(v - (float)hi);
  const unsigned short hib = __builtin_bit_cast(unsigned short, hi);
  const unsigned short lob = __builtin_bit_cast(unsigned short, lo);
  Mh[s * 256 + c] = hib;
  Ml[s * 256 + c] = lob;
  const int ks = s >> 5, w = s & 31;
  const int t = w >> 4, hh = (w >> 2) & 3, rr = w & 3;
  MTp[c * 256 + (ks * 32 + hh * 8 + t * 4 + rr)] = hib;
}

// ---------------- fused kernel ----------------
// Block = 8 waves x 32 tokens = 256 tokens. Grid = 512. LDS = 128KB (1 block/CU).
// Structure: stage ALL Mh once -> barrier -> BARRIER-FREE score loop ->
// barrier -> stage ALL MTp (latency hidden under register softmax) ->
// barrier -> BARRIER-FREE PV loop. Only 3 full-drain barriers in the kernel.
__global__ __launch_bounds__(512, 2) void fused_mem_attn(
    const float* __restrict__ x, const unsigned short* __restrict__ Mh,
    const unsigned short* __restrict__ Ml, const unsigned short* __restrict__ MTp,
    float* __restrict__ out) {
  __shared__ alignas(128) char lds[131072];

  const int tid = threadIdx.x;
  const int wave = tid >> 6;
  const int lane = tid & 63;
  const int t16 = lane & 15;
  const int h = lane >> 4;

  // Staging ownership (512 threads): physical 16B-block P = it*512+tid of a
  // 16KB slice; fetch logical L = P ^ ((P>>3)&7) (involution) -> LDS content
  // XOR-swizzled while the global_load_lds destination stays linear.
  int srcOff[2];
#pragma unroll
  for (int it = 0; it < 2; ++it) {
    const int P = it * 512 + tid;
    const int L = P ^ ((P >> 3) & 7);
    srcOff[it] = (L >> 2) * 512 + (L & 3) * 16;  // byte offset in [256 rows][64B]
  }

  // Reader-side swizzled block byte offset within a 1KB (16-row) tile.
  const int q16 = ((((t16 << 2) + h) ^ (t16 >> 1)) << 4);

  const long gtok0 = (long)blockIdx.x * 256 + (long)(wave * 32);
  const int b = (int)(gtok0 >> 14);
  const int n0 = (int)(gtok0 & 16383);
  const float* xb0 = x + ((long)b << 22) + n0 + t16;
  const float* xb1 = xb0 + 16;

  const char* MhB = (const char*)Mh;
  const char* MlB = (const char*)Ml;
  const char* MTB = (const char*)MTp;

#define XLOAD(ks)                                                              \
  _Pragma("unroll") for (int j = 0; j < 8; ++j) {                              \
    const long coff_ = (long)((ks) * 32 + h * 8 + j) << 14;                    \
    xr[(ks) % 3][0][j] = xb0[coff_];                                           \
    xr[(ks) % 3][1][j] = xb1[coff_];                                           \
  }

  float xr[3][2][8];
  f32x4 acc[14][2] = {};  // acc[13] stays exactly 0 (padding slots 208..223)

  // ---- stage ALL of Mh (8 x 16KB slices) + 2-deep x prefetch ----
#pragma unroll
  for (int ks = 0; ks < 8; ++ks)
#pragma unroll
    for (int it = 0; it < 2; ++it)
      GLOAD16(MhB + srcOff[it] + ks * 64, lds + ks * 16384 + (it * 512 + tid) * 16);
  XLOAD(0);
  XLOAD(1);
  __syncthreads();  // barrier #1: Mh resident (one-time full drain)

  // ---- score phase: S^T[slot][token], 3-pass hi/lo split. NO barriers. ----
#pragma unroll
  for (int ks = 0; ks < 8; ++ks) {
    if (ks < 6) XLOAD(ks + 2);

    bfx8 xh0, xl0, xh1, xl1;
#pragma unroll
    for (int j = 0; j < 8; ++j) {
      const float f0 = xr[ks % 3][0][j];  // per-wave counted vmcnt (compiler)
      const float f1 = xr[ks % 3][1][j];
      const __bf16 h0 = (__bf16)f0;
      const __bf16 h1 = (__bf16)f1;
      xh0[j] = h0;
      xl0[j] = (__bf16)(f0 - (float)h0);
      xh1[j] = h1;
      xl1[j] = (__bf16)(f1 - (float)h1);
    }

    const char* sb = lds + ks * 16384;
    __builtin_amdgcn_s_setprio(1);
#pragma unroll
    for (int tt = 0; tt < 13; ++tt) {  // slots >= 208 are dead (padding)
      const bfx8 ah = *(const bfx8*)(sb + tt * 1024 + q16);
      // lo-part A-fragment straight from L2 (register domain)
      const u16x8 mlu =
          *(const u16x8*)(MlB + (tt * 16 + t16) * 512 + ks * 64 + h * 16);
      const bfx8 al = __builtin_bit_cast(bfx8, mlu);
      acc[tt][0] = MFMA16(ah, xh0, acc[tt][0]);
      acc[tt][1] = MFMA16(ah, xh1, acc[tt][1]);
      acc[tt][0] = MFMA16(al, xh0, acc[tt][0]);
      acc[tt][1] = MFMA16(al, xh1, acc[tt][1]);
      acc[tt][0] = MFMA16(ah, xl0, acc[tt][0]);
      acc[tt][1] = MFMA16(ah, xl1, acc[tt][1]);
    }
    __builtin_amdgcn_s_setprio(0);
  }

  __syncthreads();  // barrier #2: all waves done reading Mh LDS

  // ---- stage ALL of MTp (7 x 16KB slices) over the dead Mh region.
  //      Latency hides under the register-only softmax below. ----
#pragma unroll
  for (int k = 0; k < 7; ++k)
#pragma unroll
    for (int it = 0; it < 2; ++it)
      GLOAD16(MTB + srcOff[it] + k * 64, lds + k * 16384 + (it * 512 + tid) * 16);

  // ---- softmax over slots (token column = lane&15; slot row = 4h+r) ----
  float inv0, inv1;
#pragma unroll
  for (int g = 0; g < 2; ++g) {
    float m = -3.0e38f;
#pragma unroll
    for (int tt = 0; tt < 12; ++tt)
#pragma unroll
      for (int r = 0; r < 4; ++r) m = fmaxf(m, acc[tt][g][r]);
#pragma unroll
    for (int r = 0; r < 4; ++r)
      if (192 + h * 4 + r < 200) m = fmaxf(m, acc[12][g][r]);
    m = fmaxf(m, __shfl_xor(m, 16, 64));
    m = fmaxf(m, __shfl_xor(m, 32, 64));
    float s = 0.f;
#pragma unroll
    for (int tt = 0; tt < 12; ++tt)
#pragma unroll
      for (int r = 0; r < 4; ++r) {
        const float p = __expf(acc[tt][g][r] - m);
        acc[tt][g][r] = p;
        s += p;
      }
#pragma unroll
    for (int r = 0; r < 4; ++r) {
      const bool ok = (192 + h * 4 + r) < 200;
      const float p = ok ? __expf(acc[12][g][r] - m) : 0.f;
      acc[12][g][r] = p;
      s += p;
    }
    s += __shfl_xor(s, 16, 64);
    s += __shfl_xor(s, 32, 64);
    if (g == 0) inv0 = 1.f / s;
    else        inv1 = 1.f / s;
  }

  // ---- repack P into PV B-fragments in registers (sigma baked into MTp) ----
  bfx8 pb[7][2];
#pragma unroll
  for (int k = 0; k < 7; ++k)
#pragma unroll
    for (int g = 0; g < 2; ++g)
#pragma unroll
      for (int j = 0; j < 4; ++j) {
        pb[k][g][j] = (__bf16)acc[2 * k][g][j];
        pb[k][g][j + 4] = (__bf16)acc[2 * k + 1][g][j];
      }

  __syncthreads();  // barrier #3: MTp resident

  // ---- PV: out^T[c][token] = sum_kidx MTp[c][kidx]*P[sigma(kidx)][token].
  //      NO barriers. kidx >= 224 skipped (P there is exactly 0). ----
  f32x4 acc2[16][2] = {};
#pragma unroll
  for (int k = 0; k < 7; ++k) {
    const char* pv = lds + k * 16384;
    __builtin_amdgcn_s_setprio(1);
#pragma unroll
    for (int ct = 0; ct < 16; ++ct) {
      const bfx8 at = *(const bfx8*)(pv + ct * 1024 + q16);
      acc2[ct][0] = MFMA16(at, pb[k][0], acc2[ct][0]);
      acc2[ct][1] = MFMA16(at, pb[k][1], acc2[ct][1]);
    }
    __builtin_amdgcn_s_setprio(0);
  }

  // ---- epilogue: normalize, store out[b][c][n] ----
  float* ob = out + ((long)b << 22) + n0 + t16;
#pragma unroll
  for (int ct = 0; ct < 16; ++ct)
#pragma unroll
    for (int r = 0; r < 4; ++r) {
      const long o = (long)(ct * 16 + h * 4 + r) << 14;
      ob[o] = acc2[ct][0][r] * inv0;
      ob[o + 16] = acc2[ct][1][r] * inv1;
    }
#undef XLOAD
}

extern "C" void kernel_launch(void* const* d_in, const int* in_sizes, int n_in,
                              void* d_out, int out_size, void* d_ws, size_t ws_size,
                              hipStream_t stream) {
  const float* x = (const float*)d_in[0];
  const float* mem = (const float*)d_in[1];
  float* out = (float*)d_out;

  unsigned short* Mh = (unsigned short*)d_ws;  // [256][256] bf16 hi
  unsigned short* Ml = Mh + 256 * 256;         // [256][256] bf16 lo
  unsigned short* MTp = Ml + 256 * 256;        // [256][256] bf16 hi, [c][kidx] permuted

  prep_mem<<<dim3(256), dim3(256), 0, stream>>>(mem, Mh, Ml, MTp);
  fused_mem_attn<<<dim3(512), dim3(512), 0, stream>>>(x, Mh, Ml, MTp, out);
}

// Round 7
// 84.037 us; speedup vs baseline: 3.7173x; 1.2627x over previous
//
#include <hip/hip_runtime.h>

typedef __bf16 bfx8 __attribute__((ext_vector_type(8)));
typedef float f32x4 __attribute__((ext_vector_type(4)));

#define MFMA16(a, b, c) __builtin_amdgcn_mfma_f32_16x16x32_bf16((a), (b), (c), 0, 0, 0)

#define GLOAD16(gp, lp)                                                        \
  __builtin_amdgcn_global_load_lds(                                            \
      (const __attribute__((address_space(1))) unsigned int*)(gp),             \
      (__attribute__((address_space(3))) unsigned int*)(lp), 16, 0, 0)

// Geometry: x (8, 256, 16384) fp32; mem (200, 256) fp32; out (8, 256, 16384) fp32.
// Slots padded 200 -> 256 with zero rows.

// ---------------- prep: mem -> bf16 hi/lo + permuted-transposed hi ----------------
// MTp[c][kidx] = hi(mem[sigma(kidx)][c]), sigma(32ks+8h+4t+r) -> slot 32ks+16t+4h+r,
// so the PV B-operand is a pure in-register repack of the score accumulators.
__global__ __launch_bounds__(256) void prep_mem(const float* __restrict__ mem,
                                                unsigned short* __restrict__ Mh,
                                                unsigned short* __restrict__ Ml,
                                                unsigned short* __restrict__ MTp) {
  const int s = blockIdx.x;   // slot (padded)
  const int c = threadIdx.x;  // channel
  const float v = (s < 200) ? mem[s * 256 + c] : 0.0f;
  const __bf16 hi = (__bf16)v;
  const __bf16 lo = (__bf16)(v - (float)hi);
  const unsigned short hib = __builtin_bit_cast(unsigned short, hi);
  const unsigned short lob = __builtin_bit_cast(unsigned short, lo);
  Mh[s * 256 + c] = hib;
  Ml[s * 256 + c] = lob;
  const int ks = s >> 5, w = s & 31;
  const int t = w >> 4, hh = (w >> 2) & 3, rr = w & 3;
  MTp[c * 256 + (ks * 32 + hh * 8 + t * 4 + rr)] = hib;
}

// ---------------- fused kernel ----------------
// Block = 16 waves x 16 tokens = 256 tokens, 1024 threads. Grid = 512.
// LDS 128KB -> 1 block/CU, but 16 waves/block = 4 waves/SIMD (vs R6's 2),
// requiring <=128 unified regs/wave (16 tokens/wave keeps peak ~110).
// Score: two half-phases (ks 0..3 / 4..7), Mh+Ml both LDS-fed.
// PV: MTp staged over dead score slices, fill hidden under softmax.
__global__ __launch_bounds__(1024, 4) void fused_mem_attn(
    const float* __restrict__ x, const unsigned short* __restrict__ Mh,
    const unsigned short* __restrict__ Ml, const unsigned short* __restrict__ MTp,
    float* __restrict__ out) {
  __shared__ alignas(128) char lds[131072];

  const int tid = threadIdx.x;   // 0..1023
  const int wave = tid >> 6;     // 0..15
  const int lane = tid & 63;
  const int t16 = lane & 15;
  const int h = lane >> 4;

  // Staging: thread owns physical 16B-block tid of each 16KB slice; fetch
  // logical L = tid ^ ((tid>>3)&7) (involution) -> LDS content XOR-swizzled
  // while the global_load_lds destination stays linear (proven R2/R6 pair).
  const int Lb = tid ^ ((tid >> 3) & 7);
  const int srcOff = (Lb >> 2) * 512 + (Lb & 3) * 16;  // byte in [256 rows][64B]

  // Reader-side swizzled block byte offset within a 1KB (16-row) tile.
  const int q16 = ((((t16 << 2) + h) ^ (t16 >> 1)) << 4);

  const long gtok0 = (long)blockIdx.x * 256 + (long)(wave * 16);
  const int b = (int)(gtok0 >> 14);
  const int n0 = (int)(gtok0 & 16383);
  const float* xb = x + ((long)b << 22) + n0 + t16;

  const char* MhB = (const char*)Mh;
  const char* MlB = (const char*)Ml;
  const char* MTB = (const char*)MTp;

  // Score slice pair for ks: hi at (ks&3)*32768, lo at +16384.
#define STAGE_S(ks)                                                            \
  {                                                                            \
    GLOAD16(MhB + srcOff + (ks) * 64, lds + ((ks) & 3) * 32768 + tid * 16);    \
    GLOAD16(MlB + srcOff + (ks) * 64,                                          \
            lds + ((ks) & 3) * 32768 + 16384 + tid * 16);                      \
  }

#define STAGE_PV(k)                                                            \
  GLOAD16(MTB + srcOff + (k) * 64, lds + (k) * 16384 + tid * 16);

#define XLOAD(ks)                                                              \
  _Pragma("unroll") for (int j = 0; j < 8; ++j) {                              \
    xr[(ks) & 1][j] = xb[(long)((ks) * 32 + h * 8 + j) << 14];                 \
  }

  float xr[2][8];
  f32x4 acc[14] = {};  // acc[13] stays exactly 0 (padding slots 208..223)

#define COMPUTE(ks)                                                            \
  {                                                                            \
    if ((ks) < 7) XLOAD((ks) + 1);                                             \
    bfx8 xh, xl;                                                               \
    _Pragma("unroll") for (int j = 0; j < 8; ++j) {                            \
      const float f = xr[(ks) & 1][j];                                         \
      const __bf16 hi_ = (__bf16)f;                                            \
      xh[j] = hi_;                                                             \
      xl[j] = (__bf16)(f - (float)hi_);                                        \
    }                                                                          \
    const char* sb = lds + ((ks) & 3) * 32768;                                 \
    __builtin_amdgcn_s_setprio(1);                                             \
    _Pragma("unroll") for (int tt = 0; tt < 13; ++tt) {                        \
      const bfx8 ah = *(const bfx8*)(sb + tt * 1024 + q16);                    \
      const bfx8 al = *(const bfx8*)(sb + 16384 + tt * 1024 + q16);            \
      acc[tt] = MFMA16(ah, xh, acc[tt]);                                       \
      acc[tt] = MFMA16(al, xh, acc[tt]);                                       \
      acc[tt] = MFMA16(ah, xl, acc[tt]);                                       \
    }                                                                          \
    __builtin_amdgcn_s_setprio(0);                                             \
  }

  // ---- phase A: stage Mh+Ml for ks 0..3 (128 KB), 1 x prefetch ----
#pragma unroll
  for (int ks = 0; ks < 4; ++ks) STAGE_S(ks);
  XLOAD(0);
  __syncthreads();  // B1: phase-A slices resident

  COMPUTE(0) COMPUTE(1) COMPUTE(2) COMPUTE(3)

  __syncthreads();  // B2: all waves done reading phase-A slices

  // ---- phase B: restage ks 4..7 over the same slices ----
#pragma unroll
  for (int ks = 4; ks < 8; ++ks) STAGE_S(ks);
  __syncthreads();  // B3: phase-B slices resident

  COMPUTE(4) COMPUTE(5) COMPUTE(6) COMPUTE(7)

  __syncthreads();  // B4: score slices dead

  // ---- stage ALL of MTp (7 x 16KB); fill hides under softmax/repack ----
#pragma unroll
  for (int k = 0; k < 7; ++k) STAGE_PV(k);

  // ---- softmax over slots (token column = lane&15; slot row = 4h+r) ----
  float m = -3.0e38f;
#pragma unroll
  for (int tt = 0; tt < 12; ++tt)
#pragma unroll
    for (int r = 0; r < 4; ++r) m = fmaxf(m, acc[tt][r]);
#pragma unroll
  for (int r = 0; r < 4; ++r)
    if (192 + h * 4 + r < 200) m = fmaxf(m, acc[12][r]);
  m = fmaxf(m, __shfl_xor(m, 16, 64));
  m = fmaxf(m, __shfl_xor(m, 32, 64));
  float s = 0.f;
#pragma unroll
  for (int tt = 0; tt < 12; ++tt)
#pragma unroll
    for (int r = 0; r < 4; ++r) {
      const float p = __expf(acc[tt][r] - m);
      acc[tt][r] = p;
      s += p;
    }
#pragma unroll
  for (int r = 0; r < 4; ++r) {
    const bool ok = (192 + h * 4 + r) < 200;
    const float p = ok ? __expf(acc[12][r] - m) : 0.f;
    acc[12][r] = p;
    s += p;
  }
  s += __shfl_xor(s, 16, 64);
  s += __shfl_xor(s, 32, 64);
  const float inv = 1.f / s;

  // ---- repack P into PV B-fragments in registers (sigma baked into MTp) ----
  bfx8 pb[7];
#pragma unroll
  for (int k = 0; k < 7; ++k)
#pragma unroll
    for (int j = 0; j < 4; ++j) {
      pb[k][j] = (__bf16)acc[2 * k][j];
      pb[k][j + 4] = (__bf16)acc[2 * k + 1][j];
    }

  __syncthreads();  // B5: MTp resident

  // ---- PV: out^T[c][token] = sum_kidx MTp[c][kidx]*P[sigma(kidx)][token].
  //      Barrier-free; kidx >= 224 skipped (P there exactly 0). ----
  f32x4 acc2[16] = {};
#pragma unroll
  for (int k = 0; k < 7; ++k) {
    const char* pv = lds + k * 16384;
    __builtin_amdgcn_s_setprio(1);
#pragma unroll
    for (int ct = 0; ct < 16; ++ct) {
      const bfx8 at = *(const bfx8*)(pv + ct * 1024 + q16);
      acc2[ct] = MFMA16(at, pb[k], acc2[ct]);
    }
    __builtin_amdgcn_s_setprio(0);
  }

  // ---- epilogue: normalize, store out[b][c][n] ----
  float* ob = out + ((long)b << 22) + n0 + t16;
#pragma unroll
  for (int ct = 0; ct < 16; ++ct)
#pragma unroll
    for (int r = 0; r < 4; ++r) {
      ob[(long)(ct * 16 + h * 4 + r) << 14] = acc2[ct][r] * inv;
    }
#undef STAGE_S
#undef STAGE_PV
#undef XLOAD
#undef COMPUTE
}

extern "C" void kernel_launch(void* const* d_in, const int* in_sizes, int n_in,
                              void* d_out, int out_size, void* d_ws, size_t ws_size,
                              hipStream_t stream) {
  const float* x = (const float*)d_in[0];
  const float* mem = (const float*)d_in[1];
  float* out = (float*)d_out;

  unsigned short* Mh = (unsigned short*)d_ws;  // [256][256] bf16 hi
  unsigned short* Ml = Mh + 256 * 256;         // [256][256] bf16 lo
  unsigned short* MTp = Ml + 256 * 256;        // [256][256] bf16 hi, [c][kidx] permuted

  prep_mem<<<dim3(256), dim3(256), 0, stream>>>(mem, Mh, Ml, MTp);
  fused_mem_attn<<<dim3(512), dim3(1024), 0, stream>>>(x, Mh, Ml, MTp, out);
}